// Round 1
// 761.405 us; speedup vs baseline: 1.0231x; 1.0231x over previous
//
#include <hip/hip_runtime.h>

#define Hdim 1024
#define Fdim 4096
#define NE   8
#define NT   2048
#define MT_MAX 16   // worst case: one expert takes all 2048 tokens / 128 rows per tile
#define KSPLIT 2    // k_down K-split; partials summed by k_combine (no atomics)

typedef __attribute__((ext_vector_type(8))) short short8;
typedef __attribute__((ext_vector_type(4))) short short4v;
typedef __attribute__((ext_vector_type(4))) float f32x4;

// fp32 -> bf16 round-to-nearest-even
__device__ __forceinline__ unsigned short bf16r(float f) {
  union { float fv; unsigned u; } v; v.fv = f;
  unsigned u = v.u;
  return (unsigned short)((u + 0x7FFFu + ((u >> 16) & 1u)) >> 16);
}

// ---------------- K1: router (4 waves/block, one token per wave) ----------------
__global__ void k_router(const float* __restrict__ x, const float* __restrict__ gw,
                         int* __restrict__ counts, int* __restrict__ sel,
                         float* __restrict__ selw) {
  int wave = threadIdx.x >> 6;
  int l    = threadIdx.x & 63;
  int t    = blockIdx.x * 4 + wave;
  const float* xp = x + (size_t)t * Hdim;
  float acc[NE];
#pragma unroll
  for (int e = 0; e < NE; e++) acc[e] = 0.f;
  for (int h = l; h < Hdim; h += 64) {
    float xv = xp[h];
#pragma unroll
    for (int e = 0; e < NE; e++) acc[e] += xv * gw[e * Hdim + h];
  }
#pragma unroll
  for (int e = 0; e < NE; e++) {
    float v = acc[e];
#pragma unroll
    for (int off = 32; off > 0; off >>= 1) v += __shfl_down(v, off, 64);
    acc[e] = v;
  }
  if (l == 0) {
    int b0 = 0; float v0 = acc[0];
    for (int e = 1; e < NE; e++) if (acc[e] > v0) { v0 = acc[e]; b0 = e; }
    int b1 = -1; float v1 = -1e30f;
    for (int e = 0; e < NE; e++) if (e != b0 && acc[e] > v1) { v1 = acc[e]; b1 = e; }
    // normalized top-2 softmax weights: w0 = p0/(p0+p1) = 1/(1+exp(l1-l0))
    float w0 = 1.f / (1.f + expf(v1 - v0));
    atomicAdd(&counts[b0], 1);
    atomicAdd(&counts[b1], 1);
    sel[2 * t]     = b0;
    sel[2 * t + 1] = b1;
    selw[2 * t]     = w0;
    selw[2 * t + 1] = 1.f - w0;
  }
}

// ---------------- K2: fused scan + scatter (single block) ----------------
__global__ void k_scatter(const int* __restrict__ counts, const int* __restrict__ sel,
                          const float* __restrict__ selw, int* __restrict__ offsets,
                          int* __restrict__ rowids, float* __restrict__ pairw,
                          int* __restrict__ tok2slot) {
  __shared__ int soff[NE];
  __shared__ int scur[NE];
  if (threadIdx.x == 0) {
    int s = 0;
    for (int e = 0; e < NE; e++) { soff[e] = s; offsets[e] = s; s += counts[e]; scur[e] = 0; }
  }
  __syncthreads();
  for (int t = threadIdx.x; t < NT; t += blockDim.x) {
#pragma unroll
    for (int j = 0; j < 2; j++) {
      int e = sel[2 * t + j];
      int p = atomicAdd(&scur[e], 1);
      int slot = soff[e] + p;
      rowids[slot]        = t;
      pairw[slot]         = selw[2 * t + j];
      tok2slot[2 * t + j] = slot;
    }
  }
}

// ---------------- K3: gate_up GEMM + gelu, fused, 1-deep register prefetch ----------------
// block tile: 128 pair-rows x 64 f-cols (gate at f, up at F+f staged as Bs rows 64..127).
// Each wave owns 64 rows (wy) x 32 f-cols (wx), computes BOTH gate and up in-register.
// LDS rows padded 32->40 shorts (80 B stride) to break the 8-way ds_read_b128 bank conflict.
__global__ __launch_bounds__(256, 2)
void k_gate_up(const float* __restrict__ x, const float* __restrict__ gup,
               const int* __restrict__ counts, const int* __restrict__ offsets,
               const int* __restrict__ rowids, unsigned short* __restrict__ hact) {
  int e  = blockIdx.y >> 4;
  int mt = blockIdx.y & 15;
  int n  = counts[e];
  if (mt * 128 >= n) return;
  int base = offsets[e];
  int row0 = mt * 128;
  int f0   = blockIdx.x * 64;

  __shared__ __align__(16) unsigned short As[128][40];
  __shared__ __align__(16) unsigned short Bs[128][40];
  __shared__ int rid[128];

  int tid = threadIdx.x;
  if (tid < 128) {
    int r = row0 + tid;
    rid[tid] = (r < n) ? rowids[base + r] : rowids[base];
  }
  __syncthreads();

  int kc   = (tid & 7) * 4;   // k offset (floats) within 32
  int trow = tid >> 3;        // 0..31
  const float* ap[4];
  const float* bp[4];
#pragma unroll
  for (int p = 0; p < 4; p++) {
    int ar = p * 32 + trow;
    ap[p] = x + (size_t)rid[ar] * Hdim + kc;
    int f = (ar < 64) ? (f0 + ar) : (Fdim + f0 + (ar - 64));
    bp[p] = gup + ((size_t)e * 2 * Fdim + f) * Hdim + kc;
  }

  int wave = tid >> 6, lane = tid & 63;
  int wy = wave >> 1, wx = wave & 1;
  int lrow = lane & 15, lk = (lane >> 4) * 8;
  f32x4 acc[4][4] = {};   // [i: row frag][j: 0,1=gate cols, 2,3=up cols]

  // preload k=0
  float4 ra[4], rb[4];
#pragma unroll
  for (int p = 0; p < 4; p++) { ra[p] = *(const float4*)(ap[p]); rb[p] = *(const float4*)(bp[p]); }

  for (int k0 = 0; k0 < Hdim; k0 += 32) {
    __syncthreads();
#pragma unroll
    for (int p = 0; p < 4; p++) {
      int ar = p * 32 + trow;
      short4v sa;
      sa.x = (short)bf16r(ra[p].x); sa.y = (short)bf16r(ra[p].y);
      sa.z = (short)bf16r(ra[p].z); sa.w = (short)bf16r(ra[p].w);
      *(short4v*)&As[ar][kc] = sa;
      short4v sb;
      sb.x = (short)bf16r(rb[p].x); sb.y = (short)bf16r(rb[p].y);
      sb.z = (short)bf16r(rb[p].z); sb.w = (short)bf16r(rb[p].w);
      *(short4v*)&Bs[ar][kc] = sb;
    }
    // issue next tile's loads; they fly across the MFMA phase + barrier
    if (k0 + 32 < Hdim) {
#pragma unroll
      for (int p = 0; p < 4; p++) {
        ra[p] = *(const float4*)(ap[p] + k0 + 32);
        rb[p] = *(const float4*)(bp[p] + k0 + 32);
      }
    }
    __syncthreads();
    short8 a[4], b[4];
#pragma unroll
    for (int i = 0; i < 4; i++) a[i] = *(const short8*)&As[wy * 64 + i * 16 + lrow][lk];
    b[0] = *(const short8*)&Bs[wx * 32 + lrow][lk];
    b[1] = *(const short8*)&Bs[wx * 32 + 16 + lrow][lk];
    b[2] = *(const short8*)&Bs[64 + wx * 32 + lrow][lk];
    b[3] = *(const short8*)&Bs[64 + wx * 32 + 16 + lrow][lk];
#pragma unroll
    for (int i = 0; i < 4; i++)
#pragma unroll
      for (int j = 0; j < 4; j++)
        acc[i][j] = __builtin_amdgcn_mfma_f32_16x16x32_bf16(a[i], b[j], acc[i][j], 0, 0, 0);
  }

  int quad = lane >> 4;
#pragma unroll
  for (int i = 0; i < 4; i++) {
#pragma unroll
    for (int r = 0; r < 4; r++) {
      int rl = row0 + wy * 64 + i * 16 + quad * 4 + r;
      if (rl < n) {
        size_t rowoff = (size_t)(base + rl) * Fdim + f0 + wx * 32;
#pragma unroll
        for (int j = 0; j < 2; j++) {
          float g = acc[i][j][r];
          float u = acc[i][j + 2][r];
          float ge = 0.5f * g * (1.f + erff(g * 0.70710678118654752f));
          hact[rowoff + j * 16 + lrow] = bf16r(u * ge);
        }
      }
    }
  }
}

// ---------------- K4: down GEMM, BK=64, K-split, NO atomics ----------------
// Writes weight-scaled partials to part[z][slot][h] with plain coalesced stores;
// k_combine sums 2 slots x KSPLIT partials per token. Removing the 16.8M global
// fp32 atomicAdds is the point of this version (they serialized at the TCC and
// caused ~200 MB of RMW write-back traffic on an 8 MB output).
__global__ __launch_bounds__(256, 2)
void k_down(const unsigned short* __restrict__ hact, const float* __restrict__ dw,
            const int* __restrict__ counts, const int* __restrict__ offsets,
            const int* __restrict__ rowids, const float* __restrict__ pairw,
            float* __restrict__ part) {
  int e  = blockIdx.y >> 4;
  int mt = blockIdx.y & 15;
  int n  = counts[e];
  if (mt * 128 >= n) return;
  int base = offsets[e];
  int row0 = mt * 128;
  int h0   = blockIdx.x * 128;
  const int KC = Fdim / KSPLIT;           // 2048
  int kbeg = blockIdx.z * KC;
  int kend = kbeg + KC;

  // BK=64: rows are 64 shorts, padded to 72 (144 B stride) for bank spread.
  __shared__ __align__(16) unsigned short As[128][72];
  __shared__ __align__(16) unsigned short Bs[128][72];

  int tid = threadIdx.x;
  int wave = tid >> 6, lane = tid & 63;
  int wy = wave >> 1, wx = wave & 1;
  int lrow = lane & 15, lkq = (lane >> 4) * 8;

  // A: 128 rows x 64 shorts = 1024 int4-chunks; 4 per thread
  const unsigned short* asrc[4];
#pragma unroll
  for (int p = 0; p < 4; p++) {
    int idx = p * 256 + tid;
    int row = idx >> 3, seg = idx & 7;
    int slot = base + row0 + row;
    if (slot > NT * 2 - 1) slot = NT * 2 - 1;  // tail rows: clamp (discarded later)
    asrc[p] = hact + (size_t)slot * Fdim + seg * 8;
  }
  // B: 128 h-rows x 64 floats = 2048 float4-chunks; 8 per thread
  const float* bsrc[8];
#pragma unroll
  for (int p = 0; p < 8; p++) {
    int idx = p * 256 + tid;
    int row = idx >> 4, seg = idx & 15;
    bsrc[p] = dw + ((size_t)e * Hdim + h0 + row) * Fdim + seg * 4;
  }

  // preload first k-chunk
  int4   raw[4];
  float4 rbw[8];
#pragma unroll
  for (int p = 0; p < 4; p++) raw[p] = *(const int4*)(asrc[p] + kbeg);
#pragma unroll
  for (int p = 0; p < 8; p++) rbw[p] = *(const float4*)(bsrc[p] + kbeg);

  f32x4 acc[4][4] = {};
  for (int k0 = kbeg; k0 < kend; k0 += 64) {
    __syncthreads();
#pragma unroll
    for (int p = 0; p < 4; p++) {
      int idx = p * 256 + tid;
      int row = idx >> 3, seg = idx & 7;
      *(int4*)&As[row][seg * 8] = raw[p];
    }
#pragma unroll
    for (int p = 0; p < 8; p++) {
      int idx = p * 256 + tid;
      int row = idx >> 4, seg = idx & 15;
      short4v sb;
      sb.x = (short)bf16r(rbw[p].x); sb.y = (short)bf16r(rbw[p].y);
      sb.z = (short)bf16r(rbw[p].z); sb.w = (short)bf16r(rbw[p].w);
      *(short4v*)&Bs[row][seg * 4] = sb;
    }
    if (k0 + 64 < kend) {
#pragma unroll
      for (int p = 0; p < 4; p++) raw[p] = *(const int4*)(asrc[p] + k0 + 64);
#pragma unroll
      for (int p = 0; p < 8; p++) rbw[p] = *(const float4*)(bsrc[p] + k0 + 64);
    }
    __syncthreads();
#pragma unroll
    for (int ks = 0; ks < 2; ks++) {
      short8 a[4], b[4];
#pragma unroll
      for (int i = 0; i < 4; i++) a[i] = *(const short8*)&As[wy * 64 + i * 16 + lrow][ks * 32 + lkq];
#pragma unroll
      for (int j = 0; j < 4; j++) b[j] = *(const short8*)&Bs[wx * 64 + j * 16 + lrow][ks * 32 + lkq];
#pragma unroll
      for (int i = 0; i < 4; i++)
#pragma unroll
        for (int j = 0; j < 4; j++)
          acc[i][j] = __builtin_amdgcn_mfma_f32_16x16x32_bf16(a[i], b[j], acc[i][j], 0, 0, 0);
    }
  }

  int quad = lane >> 4;
#pragma unroll
  for (int i = 0; i < 4; i++) {
#pragma unroll
    for (int r = 0; r < 4; r++) {
      int rl = row0 + wy * 64 + i * 16 + quad * 4 + r;
      if (rl < n) {
        int slot = base + rl;
        float wv = pairw[slot];
        float* op = part + ((size_t)blockIdx.z * (NT * 2) + slot) * Hdim + h0 + wx * 64;
#pragma unroll
        for (int j = 0; j < 4; j++)
          op[j * 16 + lrow] = wv * acc[i][j][r];
      }
    }
  }
}

// ---------------- K5: combine partials -> out (replaces atomics + out memset) ----------------
__global__ __launch_bounds__(256)
void k_combine(const float* __restrict__ part, const int* __restrict__ tok2slot,
               float* __restrict__ out) {
  int idx = blockIdx.x * 256 + threadIdx.x;   // one float4 per thread
  int t  = idx >> 8;                          // 256 float4 per token
  int hc = (idx & 255) << 2;
  int s0 = tok2slot[2 * t];
  int s1 = tok2slot[2 * t + 1];
  float4 a = *(const float4*)&part[(size_t)s0 * Hdim + hc];
  float4 b = *(const float4*)&part[((size_t)(NT * 2) + s0) * Hdim + hc];
  float4 c = *(const float4*)&part[(size_t)s1 * Hdim + hc];
  float4 d = *(const float4*)&part[((size_t)(NT * 2) + s1) * Hdim + hc];
  float4 s;
  s.x = (a.x + b.x) + (c.x + d.x);
  s.y = (a.y + b.y) + (c.y + d.y);
  s.z = (a.z + b.z) + (c.z + d.z);
  s.w = (a.w + b.w) + (c.w + d.w);
  *(float4*)&out[(size_t)t * Hdim + hc] = s;
}

extern "C" void kernel_launch(void* const* d_in, const int* in_sizes, int n_in,
                              void* d_out, int out_size, void* d_ws, size_t ws_size,
                              hipStream_t stream) {
  const float* x   = (const float*)d_in[0];   // (1, 2048, 1024)
  const float* gw  = (const float*)d_in[1];   // (8, 1024)
  const float* gup = (const float*)d_in[2];   // (8, 8192, 1024)
  const float* dwn = (const float*)d_in[3];   // (8, 1024, 4096)
  float* out = (float*)d_out;                 // (1, 2048, 1024) fp32

  char* ws = (char*)d_ws;
  int*   counts   = (int*)(ws + 0);
  int*   offsets  = (int*)(ws + 128);
  int*   sel      = (int*)(ws + 4096);                  // 2048*2 ints
  float* selw     = (float*)(ws + 4096 + 16384);        // 2048*2 floats
  int*   rowids   = (int*)(ws + 4096 + 32768);          // 4096 ints
  float* pairw    = (float*)(ws + 4096 + 49152);        // 4096 floats
  int*   tok2slot = (int*)(ws + 4096 + 65536);          // 4096 ints
  unsigned short* hact = (unsigned short*)(ws + (1 << 20));          // 4096x4096 bf16 = 32 MB
  float* part = (float*)(ws + (1 << 20) + ((size_t)32 << 20));       // KSPLIT x 4096 x 1024 f32 = 32 MB

  hipMemsetAsync(ws, 0, 4096, stream);                  // counts (+offsets)

  k_router<<<NT / 4, 256, 0, stream>>>(x, gw, counts, sel, selw);
  k_scatter<<<1, 1024, 0, stream>>>(counts, sel, selw, offsets, rowids, pairw, tok2slot);
  k_gate_up<<<dim3(Fdim / 64, NE * MT_MAX), 256, 0, stream>>>(x, gup, counts, offsets, rowids, hact);
  k_down<<<dim3(Hdim / 128, NE * MT_MAX, KSPLIT), 256, 0, stream>>>(hact, dwn, counts, offsets, rowids, pairw, part);
  k_combine<<<NT * Hdim / 4 / 256, 256, 0, stream>>>(part, tok2slot, out);
}

// Round 2
// 709.845 us; speedup vs baseline: 1.0974x; 1.0726x over previous
//
#include <hip/hip_runtime.h>

#define Hdim 1024
#define Fdim 4096
#define NE   8
#define NT   2048
#define MT_MAX 16   // worst case: one expert takes all 2048 tokens / 128 rows per tile
#define KSPLIT 2    // k_down K-split; partials summed by k_combine (no atomics)

typedef __attribute__((ext_vector_type(8))) short short8;
typedef __attribute__((ext_vector_type(4))) short short4v;
typedef __attribute__((ext_vector_type(4))) float f32x4;

// fp32 -> bf16 round-to-nearest-even
__device__ __forceinline__ unsigned short bf16r(float f) {
  union { float fv; unsigned u; } v; v.fv = f;
  unsigned u = v.u;
  return (unsigned short)((u + 0x7FFFu + ((u >> 16) & 1u)) >> 16);
}

// async global->LDS, 16 B per lane; LDS dest = wave-uniform base + lane*16
__device__ __forceinline__ void gl_lds16(const void* g, void* l) {
  __builtin_amdgcn_global_load_lds(
      (const __attribute__((address_space(1))) unsigned int*)g,
      (__attribute__((address_space(3))) unsigned int*)l, 16, 0, 0);
}

// ---------------- K0: fp32 -> bf16 streaming converter ----------------
__global__ __launch_bounds__(256)
void k_cvt(const float* __restrict__ src, unsigned short* __restrict__ dst, int n4) {
  int stride = gridDim.x * 256;
  for (int i = blockIdx.x * 256 + threadIdx.x; i < n4; i += stride) {
    float4 v = *(const float4*)(src + (size_t)i * 4);
    short4v s;
    s.x = (short)bf16r(v.x); s.y = (short)bf16r(v.y);
    s.z = (short)bf16r(v.z); s.w = (short)bf16r(v.w);
    *(short4v*)(dst + (size_t)i * 4) = s;
  }
}

// ---------------- K1: router (4 waves/block, one token per wave) ----------------
__global__ void k_router(const float* __restrict__ x, const float* __restrict__ gw,
                         int* __restrict__ counts, int* __restrict__ sel,
                         float* __restrict__ selw) {
  int wave = threadIdx.x >> 6;
  int l    = threadIdx.x & 63;
  int t    = blockIdx.x * 4 + wave;
  const float* xp = x + (size_t)t * Hdim;
  float acc[NE];
#pragma unroll
  for (int e = 0; e < NE; e++) acc[e] = 0.f;
  for (int h = l; h < Hdim; h += 64) {
    float xv = xp[h];
#pragma unroll
    for (int e = 0; e < NE; e++) acc[e] += xv * gw[e * Hdim + h];
  }
#pragma unroll
  for (int e = 0; e < NE; e++) {
    float v = acc[e];
#pragma unroll
    for (int off = 32; off > 0; off >>= 1) v += __shfl_down(v, off, 64);
    acc[e] = v;
  }
  if (l == 0) {
    int b0 = 0; float v0 = acc[0];
    for (int e = 1; e < NE; e++) if (acc[e] > v0) { v0 = acc[e]; b0 = e; }
    int b1 = -1; float v1 = -1e30f;
    for (int e = 0; e < NE; e++) if (e != b0 && acc[e] > v1) { v1 = acc[e]; b1 = e; }
    float w0 = 1.f / (1.f + expf(v1 - v0));
    atomicAdd(&counts[b0], 1);
    atomicAdd(&counts[b1], 1);
    sel[2 * t]     = b0;
    sel[2 * t + 1] = b1;
    selw[2 * t]     = w0;
    selw[2 * t + 1] = 1.f - w0;
  }
}

// ---------------- K2: fused scan + scatter (single block) ----------------
__global__ void k_scatter(const int* __restrict__ counts, const int* __restrict__ sel,
                          const float* __restrict__ selw, int* __restrict__ offsets,
                          int* __restrict__ rowids, float* __restrict__ pairw,
                          int* __restrict__ tok2slot) {
  __shared__ int soff[NE];
  __shared__ int scur[NE];
  if (threadIdx.x == 0) {
    int s = 0;
    for (int e = 0; e < NE; e++) { soff[e] = s; offsets[e] = s; s += counts[e]; scur[e] = 0; }
  }
  __syncthreads();
  for (int t = threadIdx.x; t < NT; t += blockDim.x) {
#pragma unroll
    for (int j = 0; j < 2; j++) {
      int e = sel[2 * t + j];
      int p = atomicAdd(&scur[e], 1);
      int slot = soff[e] + p;
      rowids[slot]        = t;
      pairw[slot]         = selw[2 * t + j];
      tok2slot[2 * t + j] = slot;
    }
  }
}

// ---------------- K3 (bf16): gate_up GEMM + gelu via global_load_lds ----------------
// m97 structure: stage (async DMA) -> barrier -> ds_read(swizzled)+MFMA -> barrier.
// BK=64. LDS linear [128][64]; logical (r,c16) lives at chunk r*8 + (c16 ^ (r&7))
// (rule 21: linear DMA dest + inverse-swizzled SOURCE + swizzled READ).
__global__ __launch_bounds__(256, 2)
void k_gate_up_bf(const unsigned short* __restrict__ xbf, const unsigned short* __restrict__ wbf,
                  const int* __restrict__ counts, const int* __restrict__ offsets,
                  const int* __restrict__ rowids, unsigned short* __restrict__ hact) {
  int e  = blockIdx.y >> 4;
  int mt = blockIdx.y & 15;
  int n  = counts[e];
  if (mt * 128 >= n) return;
  int base = offsets[e];
  int row0 = mt * 128;
  int f0   = blockIdx.x * 64;

  __shared__ __align__(16) unsigned short As[128][64];
  __shared__ __align__(16) unsigned short Bs[128][64];
  __shared__ int rid[128];

  int tid = threadIdx.x;
  if (tid < 128) {
    int r = row0 + tid;
    rid[tid] = (r < n) ? rowids[base + r] : rowids[base];
  }
  __syncthreads();

  // staging: chunk q = p*256 + tid; row R = q>>3 = p*32 + (tid>>3); phys col = tid&7
  int crow  = tid >> 3;
  int cphys = tid & 7;
  const unsigned short* sa[4];
  const unsigned short* sb[4];
#pragma unroll
  for (int p = 0; p < 4; p++) {
    int R = p * 32 + crow;
    int csrc = cphys ^ (R & 7);                 // inverse swizzle on global source
    sa[p] = xbf + (size_t)rid[R] * Hdim + csrc * 8;
    int fr = (R < 64) ? (f0 + R) : (Fdim + f0 + (R - 64));
    sb[p] = wbf + ((size_t)e * 2 * Fdim + fr) * Hdim + csrc * 8;
  }
  int w = tid >> 6, lane = tid & 63;
  unsigned short* da[4];
  unsigned short* db[4];
#pragma unroll
  for (int p = 0; p < 4; p++) {
    da[p] = &As[0][0] + p * 2048 + w * 512;     // wave-uniform; HW adds lane*16B
    db[p] = &Bs[0][0] + p * 2048 + w * 512;
  }

  int wy = w >> 1, wx = w & 1;
  int lrow = lane & 15, cq = lane >> 4;
  f32x4 acc[4][4] = {};   // [i: row frag][j: 0,1=gate cols, 2,3=up cols]

  for (int k0 = 0; k0 < Hdim; k0 += 64) {
#pragma unroll
    for (int p = 0; p < 4; p++) gl_lds16(sa[p] + k0, da[p]);
#pragma unroll
    for (int p = 0; p < 4; p++) gl_lds16(sb[p] + k0, db[p]);
    __syncthreads();   // compiler drains vmcnt+lgkmcnt here
#pragma unroll
    for (int ks = 0; ks < 2; ks++) {
      int soff = ((ks * 4 + cq) ^ (lrow & 7)) * 8;   // all frag rows ≡ lrow (mod 8)
      short8 a[4], b[4];
#pragma unroll
      for (int i = 0; i < 4; i++) a[i] = *(const short8*)&As[wy * 64 + i * 16 + lrow][soff];
      b[0] = *(const short8*)&Bs[wx * 32 + lrow][soff];
      b[1] = *(const short8*)&Bs[wx * 32 + 16 + lrow][soff];
      b[2] = *(const short8*)&Bs[64 + wx * 32 + lrow][soff];
      b[3] = *(const short8*)&Bs[64 + wx * 32 + 16 + lrow][soff];
#pragma unroll
      for (int i = 0; i < 4; i++)
#pragma unroll
        for (int j = 0; j < 4; j++)
          acc[i][j] = __builtin_amdgcn_mfma_f32_16x16x32_bf16(a[i], b[j], acc[i][j], 0, 0, 0);
    }
    __syncthreads();
  }

  int quad = lane >> 4;
#pragma unroll
  for (int i = 0; i < 4; i++) {
#pragma unroll
    for (int r = 0; r < 4; r++) {
      int rl = row0 + wy * 64 + i * 16 + quad * 4 + r;
      if (rl < n) {
        size_t rowoff = (size_t)(base + rl) * Fdim + f0 + wx * 32;
#pragma unroll
        for (int j = 0; j < 2; j++) {
          float g = acc[i][j][r];
          float u = acc[i][j + 2][r];
          float ge = 0.5f * g * (1.f + erff(g * 0.70710678118654752f));
          hact[rowoff + j * 16 + lrow] = bf16r(u * ge);
        }
      }
    }
  }
}

// ---------------- K4 (bf16): down GEMM via global_load_lds, K-split, no atomics ----------------
__global__ __launch_bounds__(256, 2)
void k_down_bf(const unsigned short* __restrict__ hact, const unsigned short* __restrict__ dbf,
               const int* __restrict__ counts, const int* __restrict__ offsets,
               const float* __restrict__ pairw, float* __restrict__ part) {
  int e  = blockIdx.y >> 4;
  int mt = blockIdx.y & 15;
  int n  = counts[e];
  if (mt * 128 >= n) return;
  int base = offsets[e];
  int row0 = mt * 128;
  int h0   = blockIdx.x * 128;
  const int KC = Fdim / KSPLIT;   // 2048
  int kbeg = blockIdx.z * KC;
  int kend = kbeg + KC;

  __shared__ __align__(16) unsigned short As[128][64];
  __shared__ __align__(16) unsigned short Bs[128][64];

  int tid = threadIdx.x;
  int crow  = tid >> 3;
  int cphys = tid & 7;
  const unsigned short* sa[4];
  const unsigned short* sb[4];
#pragma unroll
  for (int p = 0; p < 4; p++) {
    int R = p * 32 + crow;
    int csrc = cphys ^ (R & 7);
    int slot = base + row0 + R;
    if (slot > NT * 2 - 1) slot = NT * 2 - 1;   // tail rows: clamp (discarded later)
    sa[p] = hact + (size_t)slot * Fdim + csrc * 8;
    sb[p] = dbf + ((size_t)e * Hdim + h0 + R) * Fdim + csrc * 8;
  }
  int w = tid >> 6, lane = tid & 63;
  unsigned short* da[4];
  unsigned short* db[4];
#pragma unroll
  for (int p = 0; p < 4; p++) {
    da[p] = &As[0][0] + p * 2048 + w * 512;
    db[p] = &Bs[0][0] + p * 2048 + w * 512;
  }

  int wy = w >> 1, wx = w & 1;
  int lrow = lane & 15, cq = lane >> 4;
  f32x4 acc[4][4] = {};

  for (int k0 = kbeg; k0 < kend; k0 += 64) {
#pragma unroll
    for (int p = 0; p < 4; p++) gl_lds16(sa[p] + k0, da[p]);
#pragma unroll
    for (int p = 0; p < 4; p++) gl_lds16(sb[p] + k0, db[p]);
    __syncthreads();
#pragma unroll
    for (int ks = 0; ks < 2; ks++) {
      int soff = ((ks * 4 + cq) ^ (lrow & 7)) * 8;
      short8 a[4], b[4];
#pragma unroll
      for (int i = 0; i < 4; i++) a[i] = *(const short8*)&As[wy * 64 + i * 16 + lrow][soff];
#pragma unroll
      for (int j = 0; j < 4; j++) b[j] = *(const short8*)&Bs[wx * 64 + j * 16 + lrow][soff];
#pragma unroll
      for (int i = 0; i < 4; i++)
#pragma unroll
        for (int j = 0; j < 4; j++)
          acc[i][j] = __builtin_amdgcn_mfma_f32_16x16x32_bf16(a[i], b[j], acc[i][j], 0, 0, 0);
    }
    __syncthreads();
  }

  int quad = lane >> 4;
#pragma unroll
  for (int i = 0; i < 4; i++) {
#pragma unroll
    for (int r = 0; r < 4; r++) {
      int rl = row0 + wy * 64 + i * 16 + quad * 4 + r;
      if (rl < n) {
        int slot = base + rl;
        float wv = pairw[slot];
        float* op = part + ((size_t)blockIdx.z * (NT * 2) + slot) * Hdim + h0 + wx * 64;
#pragma unroll
        for (int j = 0; j < 4; j++)
          op[j * 16 + lrow] = wv * acc[i][j][r];
      }
    }
  }
}

// ---------------- Fallback (fp32-input) GEMMs, used only if ws too small ----------------
__global__ __launch_bounds__(256, 2)
void k_gate_up_v1(const float* __restrict__ x, const float* __restrict__ gup,
                  const int* __restrict__ counts, const int* __restrict__ offsets,
                  const int* __restrict__ rowids, unsigned short* __restrict__ hact) {
  int e  = blockIdx.y >> 4;
  int mt = blockIdx.y & 15;
  int n  = counts[e];
  if (mt * 128 >= n) return;
  int base = offsets[e];
  int row0 = mt * 128;
  int f0   = blockIdx.x * 64;

  __shared__ __align__(16) unsigned short As[128][40];
  __shared__ __align__(16) unsigned short Bs[128][40];
  __shared__ int rid[128];

  int tid = threadIdx.x;
  if (tid < 128) {
    int r = row0 + tid;
    rid[tid] = (r < n) ? rowids[base + r] : rowids[base];
  }
  __syncthreads();

  int kc   = (tid & 7) * 4;
  int trow = tid >> 3;
  const float* ap[4];
  const float* bp[4];
#pragma unroll
  for (int p = 0; p < 4; p++) {
    int ar = p * 32 + trow;
    ap[p] = x + (size_t)rid[ar] * Hdim + kc;
    int f = (ar < 64) ? (f0 + ar) : (Fdim + f0 + (ar - 64));
    bp[p] = gup + ((size_t)e * 2 * Fdim + f) * Hdim + kc;
  }

  int wave = tid >> 6, lane = tid & 63;
  int wy = wave >> 1, wx = wave & 1;
  int lrow = lane & 15, lk = (lane >> 4) * 8;
  f32x4 acc[4][4] = {};

  float4 ra[4], rb[4];
#pragma unroll
  for (int p = 0; p < 4; p++) { ra[p] = *(const float4*)(ap[p]); rb[p] = *(const float4*)(bp[p]); }

  for (int k0 = 0; k0 < Hdim; k0 += 32) {
    __syncthreads();
#pragma unroll
    for (int p = 0; p < 4; p++) {
      int ar = p * 32 + trow;
      short4v sa;
      sa.x = (short)bf16r(ra[p].x); sa.y = (short)bf16r(ra[p].y);
      sa.z = (short)bf16r(ra[p].z); sa.w = (short)bf16r(ra[p].w);
      *(short4v*)&As[ar][kc] = sa;
      short4v sbv;
      sbv.x = (short)bf16r(rb[p].x); sbv.y = (short)bf16r(rb[p].y);
      sbv.z = (short)bf16r(rb[p].z); sbv.w = (short)bf16r(rb[p].w);
      *(short4v*)&Bs[ar][kc] = sbv;
    }
    if (k0 + 32 < Hdim) {
#pragma unroll
      for (int p = 0; p < 4; p++) {
        ra[p] = *(const float4*)(ap[p] + k0 + 32);
        rb[p] = *(const float4*)(bp[p] + k0 + 32);
      }
    }
    __syncthreads();
    short8 a[4], b[4];
#pragma unroll
    for (int i = 0; i < 4; i++) a[i] = *(const short8*)&As[wy * 64 + i * 16 + lrow][lk];
    b[0] = *(const short8*)&Bs[wx * 32 + lrow][lk];
    b[1] = *(const short8*)&Bs[wx * 32 + 16 + lrow][lk];
    b[2] = *(const short8*)&Bs[64 + wx * 32 + lrow][lk];
    b[3] = *(const short8*)&Bs[64 + wx * 32 + 16 + lrow][lk];
#pragma unroll
    for (int i = 0; i < 4; i++)
#pragma unroll
      for (int j = 0; j < 4; j++)
        acc[i][j] = __builtin_amdgcn_mfma_f32_16x16x32_bf16(a[i], b[j], acc[i][j], 0, 0, 0);
  }

  int quad = lane >> 4;
#pragma unroll
  for (int i = 0; i < 4; i++) {
#pragma unroll
    for (int r = 0; r < 4; r++) {
      int rl = row0 + wy * 64 + i * 16 + quad * 4 + r;
      if (rl < n) {
        size_t rowoff = (size_t)(base + rl) * Fdim + f0 + wx * 32;
#pragma unroll
        for (int j = 0; j < 2; j++) {
          float g = acc[i][j][r];
          float u = acc[i][j + 2][r];
          float ge = 0.5f * g * (1.f + erff(g * 0.70710678118654752f));
          hact[rowoff + j * 16 + lrow] = bf16r(u * ge);
        }
      }
    }
  }
}

__global__ __launch_bounds__(256, 2)
void k_down_v1(const unsigned short* __restrict__ hact, const float* __restrict__ dw,
               const int* __restrict__ counts, const int* __restrict__ offsets,
               const float* __restrict__ pairw, float* __restrict__ part) {
  int e  = blockIdx.y >> 4;
  int mt = blockIdx.y & 15;
  int n  = counts[e];
  if (mt * 128 >= n) return;
  int base = offsets[e];
  int row0 = mt * 128;
  int h0   = blockIdx.x * 128;
  const int KC = Fdim / KSPLIT;
  int kbeg = blockIdx.z * KC;
  int kend = kbeg + KC;

  __shared__ __align__(16) unsigned short As[128][72];
  __shared__ __align__(16) unsigned short Bs[128][72];

  int tid = threadIdx.x;
  int wave = tid >> 6, lane = tid & 63;
  int wy = wave >> 1, wx = wave & 1;
  int lrow = lane & 15, lkq = (lane >> 4) * 8;

  const unsigned short* asrc[4];
#pragma unroll
  for (int p = 0; p < 4; p++) {
    int idx = p * 256 + tid;
    int row = idx >> 3, seg = idx & 7;
    int slot = base + row0 + row;
    if (slot > NT * 2 - 1) slot = NT * 2 - 1;
    asrc[p] = hact + (size_t)slot * Fdim + seg * 8;
  }
  const float* bsrc[8];
#pragma unroll
  for (int p = 0; p < 8; p++) {
    int idx = p * 256 + tid;
    int row = idx >> 4, seg = idx & 15;
    bsrc[p] = dw + ((size_t)e * Hdim + h0 + row) * Fdim + seg * 4;
  }

  int4   raw[4];
  float4 rbw[8];
#pragma unroll
  for (int p = 0; p < 4; p++) raw[p] = *(const int4*)(asrc[p] + kbeg);
#pragma unroll
  for (int p = 0; p < 8; p++) rbw[p] = *(const float4*)(bsrc[p] + kbeg);

  f32x4 acc[4][4] = {};
  for (int k0 = kbeg; k0 < kend; k0 += 64) {
    __syncthreads();
#pragma unroll
    for (int p = 0; p < 4; p++) {
      int idx = p * 256 + tid;
      int row = idx >> 3, seg = idx & 7;
      *(int4*)&As[row][seg * 8] = raw[p];
    }
#pragma unroll
    for (int p = 0; p < 8; p++) {
      int idx = p * 256 + tid;
      int row = idx >> 4, seg = idx & 15;
      short4v sbv;
      sbv.x = (short)bf16r(rbw[p].x); sbv.y = (short)bf16r(rbw[p].y);
      sbv.z = (short)bf16r(rbw[p].z); sbv.w = (short)bf16r(rbw[p].w);
      *(short4v*)&Bs[row][seg * 4] = sbv;
    }
    if (k0 + 64 < kend) {
#pragma unroll
      for (int p = 0; p < 4; p++) raw[p] = *(const int4*)(asrc[p] + k0 + 64);
#pragma unroll
      for (int p = 0; p < 8; p++) rbw[p] = *(const float4*)(bsrc[p] + k0 + 64);
    }
    __syncthreads();
#pragma unroll
    for (int ks = 0; ks < 2; ks++) {
      short8 a[4], b[4];
#pragma unroll
      for (int i = 0; i < 4; i++) a[i] = *(const short8*)&As[wy * 64 + i * 16 + lrow][ks * 32 + lkq];
#pragma unroll
      for (int j = 0; j < 4; j++) b[j] = *(const short8*)&Bs[wx * 64 + j * 16 + lrow][ks * 32 + lkq];
#pragma unroll
      for (int i = 0; i < 4; i++)
#pragma unroll
        for (int j = 0; j < 4; j++)
          acc[i][j] = __builtin_amdgcn_mfma_f32_16x16x32_bf16(a[i], b[j], acc[i][j], 0, 0, 0);
    }
  }

  int quad = lane >> 4;
#pragma unroll
  for (int i = 0; i < 4; i++) {
#pragma unroll
    for (int r = 0; r < 4; r++) {
      int rl = row0 + wy * 64 + i * 16 + quad * 4 + r;
      if (rl < n) {
        int slot = base + rl;
        float wv = pairw[slot];
        float* op = part + ((size_t)blockIdx.z * (NT * 2) + slot) * Hdim + h0 + wx * 64;
#pragma unroll
        for (int j = 0; j < 4; j++)
          op[j * 16 + lrow] = wv * acc[i][j][r];
      }
    }
  }
}

// ---------------- K5: combine partials -> out ----------------
__global__ __launch_bounds__(256)
void k_combine(const float* __restrict__ part, const int* __restrict__ tok2slot,
               float* __restrict__ out) {
  int idx = blockIdx.x * 256 + threadIdx.x;
  int t  = idx >> 8;
  int hc = (idx & 255) << 2;
  int s0 = tok2slot[2 * t];
  int s1 = tok2slot[2 * t + 1];
  float4 a = *(const float4*)&part[(size_t)s0 * Hdim + hc];
  float4 b = *(const float4*)&part[((size_t)(NT * 2) + s0) * Hdim + hc];
  float4 c = *(const float4*)&part[(size_t)s1 * Hdim + hc];
  float4 d = *(const float4*)&part[((size_t)(NT * 2) + s1) * Hdim + hc];
  float4 s;
  s.x = (a.x + b.x) + (c.x + d.x);
  s.y = (a.y + b.y) + (c.y + d.y);
  s.z = (a.z + b.z) + (c.z + d.z);
  s.w = (a.w + b.w) + (c.w + d.w);
  *(float4*)&out[(size_t)t * Hdim + hc] = s;
}

extern "C" void kernel_launch(void* const* d_in, const int* in_sizes, int n_in,
                              void* d_out, int out_size, void* d_ws, size_t ws_size,
                              hipStream_t stream) {
  const float* x   = (const float*)d_in[0];   // (1, 2048, 1024)
  const float* gw  = (const float*)d_in[1];   // (8, 1024)
  const float* gup = (const float*)d_in[2];   // (8, 8192, 1024)
  const float* dwn = (const float*)d_in[3];   // (8, 1024, 4096)
  float* out = (float*)d_out;                 // (1, 2048, 1024) fp32

  char* ws = (char*)d_ws;
  int*   counts   = (int*)(ws + 0);
  int*   offsets  = (int*)(ws + 128);
  int*   sel      = (int*)(ws + 4096);
  float* selw     = (float*)(ws + 4096 + 16384);
  int*   rowids   = (int*)(ws + 4096 + 32768);
  float* pairw    = (float*)(ws + 4096 + 49152);
  int*   tok2slot = (int*)(ws + 4096 + 65536);
  unsigned short* hact = (unsigned short*)(ws + (1 << 20));                 // 32 MB
  float* part = (float*)(ws + (1 << 20) + ((size_t)32 << 20));              // 32 MB
  unsigned short* xbf = (unsigned short*)(ws + (1 << 20) + ((size_t)64 << 20));   // 4 MB
  unsigned short* wbf = (unsigned short*)(ws + (1 << 20) + ((size_t)68 << 20));   // 128 MB (reused for dbf)
  unsigned short* dbf = wbf;   // down_w bf16 overwrites wbf AFTER k_gate_up_bf (stream-ordered)

  const size_t NEED = (size_t)(1 << 20) + ((size_t)68 << 20) + ((size_t)128 << 20);

  hipMemsetAsync(ws, 0, 4096, stream);

  k_router<<<NT / 4, 256, 0, stream>>>(x, gw, counts, sel, selw);
  k_scatter<<<1, 1024, 0, stream>>>(counts, sel, selw, offsets, rowids, pairw, tok2slot);

  if (ws_size >= NEED) {
    k_cvt<<<2048, 256, 0, stream>>>(x, xbf, NT * Hdim / 4);
    k_cvt<<<2048, 256, 0, stream>>>(gup, wbf, NE * 2 * Fdim * Hdim / 4);
    k_gate_up_bf<<<dim3(Fdim / 64, NE * MT_MAX), 256, 0, stream>>>(xbf, wbf, counts, offsets, rowids, hact);
    k_cvt<<<2048, 256, 0, stream>>>(dwn, dbf, NE * Hdim * Fdim / 4);
    k_down_bf<<<dim3(Hdim / 128, NE * MT_MAX, KSPLIT), 256, 0, stream>>>(hact, dbf, counts, offsets, pairw, part);
  } else {
    k_gate_up_v1<<<dim3(Fdim / 64, NE * MT_MAX), 256, 0, stream>>>(x, gup, counts, offsets, rowids, hact);
    k_down_v1<<<dim3(Hdim / 128, NE * MT_MAX, KSPLIT), 256, 0, stream>>>(hact, dwn, counts, offsets, pairw, part);
  }
  k_combine<<<NT * Hdim / 4 / 256, 256, 0, stream>>>(part, tok2slot, out);
}